// Round 6
// baseline (92.622 us; speedup 1.0000x reference)
//
#include <hip/hip_runtime.h>
#include <math.h>

// x: (B,S,G,D) f32, norm_scale: (G,D) f32, conv_kernel: (K, G*D) f32
// out: (B,S,G,D) f32.  B=4, S=4096, G=4, D=1024, K=4, C=4096
constexpr int B = 4;
constexpr int S = 4096;
constexpr int G = 4;
constexpr int D = 1024;
constexpr int K = 4;
constexpr int C = G * D;
constexpr int STRIP = 16;            // s-rows per wave: 4096 waves = all slots
constexpr float EPS = 1e-6f;

typedef float v4f __attribute__((ext_vector_type(4)));

// Wave-autonomous fused RMSNorm + causal depthwise conv1d (K=4) + SiLU.
// One wave owns a full (b,g,s-strip): 64 lanes x 16 channels = D = 1024, so
// the RMS reduce is wave-internal (shfl only). NO __syncthreads, NO LDS.
// 4096 independent waves (fills all 16-waves/CU slots at VGPR=104);
// per-wave 3-row register window + 1-row prefetch.
__global__ __launch_bounds__(256)
void shortconv_wave_kernel(const float* __restrict__ x,
                           const float* __restrict__ scale,
                           const float* __restrict__ w,
                           float* __restrict__ out)
{
    const int tid   = threadIdx.x;
    const int lane  = tid & 63;
    const int wid   = tid >> 6;
    const int gw    = blockIdx.x * 4 + wid;   // global wave id
    const int nstr  = S / STRIP;              // strips per (b,g)
    const int strip = gw % nstr;
    const int bg    = gw / nstr;              // 0..15
    const int b     = bg >> 2;
    const int g     = bg & 3;
    const int s0    = strip * STRIP;
    const int send  = s0 + STRIP;

    // lane owns channels g*D + lane*4 + j*256, j=0..3 (each load coalesced 1KB)
    const size_t base = (size_t)b * S * C + (size_t)g * D + (size_t)(lane * 4);
    const int    coff = g * D + lane * 4;

    v4f sc[4], wt0[4], wt1[4], wt2[4], wt3[4];
    #pragma unroll
    for (int j = 0; j < 4; ++j) {
        sc[j]  = *(const v4f*)(scale + coff + j * 256);
        wt0[j] = *(const v4f*)(w + 0 * C + coff + j * 256);
        wt1[j] = *(const v4f*)(w + 1 * C + coff + j * 256);
        wt2[j] = *(const v4f*)(w + 2 * C + coff + j * 256);
        wt3[j] = *(const v4f*)(w + 3 * C + coff + j * 256);
    }

    v4f win0[4], win1[4], win2[4], cur[4], nxt[4];
    #pragma unroll
    for (int j = 0; j < 4; ++j) {
        win0[j] = (v4f)0.f; win1[j] = (v4f)0.f; win2[j] = (v4f)0.f;
        nxt[j] = (v4f)0.f;
    }

    {   // load first pipeline row (s0-3); zero if before sequence start
        const int s = s0 - 3;
        #pragma unroll
        for (int j = 0; j < 4; ++j)
            cur[j] = (s >= 0) ? *(const v4f*)(x + base + (size_t)s * C + j * 256)
                              : (v4f)0.f;
    }

    for (int s = s0 - 3; s < send; ++s) {
        // Prefetch next row; overlaps with this row's reduce/compute.
        const int sn = s + 1;
        if (sn < send) {
            #pragma unroll
            for (int j = 0; j < 4; ++j)
                nxt[j] = (sn >= 0) ? *(const v4f*)(x + base + (size_t)sn * C + j * 256)
                                   : (v4f)0.f;
        }

        // Wave-local sum of squares over D=1024 (16 per lane + 6-step butterfly).
        v4f a = cur[0] * cur[0];
        a += cur[1] * cur[1];
        a += cur[2] * cur[2];
        a += cur[3] * cur[3];
        float local = a.x + a.y + a.z + a.w;
        #pragma unroll
        for (int off = 32; off > 0; off >>= 1)
            local += __shfl_xor(local, off, 64);
        const float invr = rsqrtf(local * (1.0f / D) + EPS);

        v4f nv[4];
        #pragma unroll
        for (int j = 0; j < 4; ++j)
            nv[j] = cur[j] * (invr * sc[j]);

        if (s >= s0) {
            #pragma unroll
            for (int j = 0; j < 4; ++j) {
                v4f y = wt0[j] * win0[j] + wt1[j] * win1[j]
                      + wt2[j] * win2[j] + wt3[j] * nv[j];
                y.x *= __builtin_amdgcn_rcpf(1.f + __expf(-y.x));
                y.y *= __builtin_amdgcn_rcpf(1.f + __expf(-y.y));
                y.z *= __builtin_amdgcn_rcpf(1.f + __expf(-y.z));
                y.w *= __builtin_amdgcn_rcpf(1.f + __expf(-y.w));
                __builtin_nontemporal_store(y, (v4f*)(out + base + (size_t)s * C + j * 256));
            }
        }

        #pragma unroll
        for (int j = 0; j < 4; ++j) {
            win0[j] = win1[j];
            win1[j] = win2[j];
            win2[j] = nv[j];
            cur[j]  = nxt[j];
        }
    }
}

extern "C" void kernel_launch(void* const* d_in, const int* in_sizes, int n_in,
                              void* d_out, int out_size, void* d_ws, size_t ws_size,
                              hipStream_t stream) {
    const float* x     = (const float*)d_in[0];
    const float* scale = (const float*)d_in[1];
    const float* w     = (const float*)d_in[2];
    float* out         = (float*)d_out;

    const int total_waves = (S / STRIP) * B * G;   // 4096
    dim3 grid(total_waves / 4);                    // 1024 blocks of 4 waves
    dim3 block(256);
    shortconv_wave_kernel<<<grid, block, 0, stream>>>(x, scale, w, out);
}

// Round 7
// 87.833 us; speedup vs baseline: 1.0545x; 1.0545x over previous
//
#include <hip/hip_runtime.h>
#include <math.h>

// x: (B,S,G,D) f32, norm_scale: (G,D) f32, conv_kernel: (K, G*D) f32
// out: (B,S,G,D) f32.  B=4, S=4096, G=4, D=1024, K=4, C=4096
constexpr int B = 4;
constexpr int S = 4096;
constexpr int G = 4;
constexpr int D = 1024;
constexpr int K = 4;
constexpr int C = G * D;
constexpr int STRIP = 32;            // s-rows per wave: 2048 waves, 8/CU
constexpr float EPS = 1e-6f;

typedef float v4f __attribute__((ext_vector_type(4)));

// Wave-autonomous fused RMSNorm + causal depthwise conv1d (K=4) + SiLU.
// One wave owns a (b,g,32-row strip): 64 lanes x 16 ch = D = 1024; RMS reduce
// is wave-internal shfl. NO barriers, NO LDS. 3-row-deep load pipeline:
// rows s+1..s+3 in flight while row s is reduced (hides ~900cy HBM latency).
// norm_scale is folded into the conv taps at startup.
__global__ __launch_bounds__(256)
void shortconv_wave_kernel(const float* __restrict__ x,
                           const float* __restrict__ scale,
                           const float* __restrict__ w,
                           float* __restrict__ out)
{
    const int tid   = threadIdx.x;
    const int lane  = tid & 63;
    const int wid   = tid >> 6;
    const int gw    = blockIdx.x * 4 + wid;   // global wave id, 0..2047
    const int nstr  = S / STRIP;              // 128 strips per (b,g)
    const int strip = gw & (nstr - 1);
    const int bg    = gw >> 7;                // 0..15
    const int b     = bg >> 2;
    const int g     = bg & 3;
    const int s0    = strip * STRIP;
    const int send  = s0 + STRIP;

    // lane owns channels g*D + lane*4 + j*256 (each j-chunk = 1KB coalesced)
    const size_t base = (size_t)b * S * C + (size_t)g * D + (size_t)(lane * 4);
    const int    coff = g * D + lane * 4;

    // Conv taps with the RMSNorm scale folded in: wt'_k = wt_k * sc.
    v4f wt0[4], wt1[4], wt2[4], wt3[4];
    #pragma unroll
    for (int j = 0; j < 4; ++j) {
        const v4f sc = *(const v4f*)(scale + coff + j * 256);
        wt0[j] = *(const v4f*)(w + 0 * C + coff + j * 256) * sc;
        wt1[j] = *(const v4f*)(w + 1 * C + coff + j * 256) * sc;
        wt2[j] = *(const v4f*)(w + 2 * C + coff + j * 256) * sc;
        wt3[j] = *(const v4f*)(w + 3 * C + coff + j * 256) * sc;
    }

    // n0..n2: normalized (x*invr) rows s-3,s-2,s-1.  cur: raw row s.
    // f1,f2: raw rows s+1,s+2 in flight.  f3 issued inside the loop.
    v4f n0[4], n1[4], n2[4], cur[4], f1[4], f2[4];
    #pragma unroll
    for (int j = 0; j < 4; ++j) { n0[j] = (v4f)0.f; n1[j] = (v4f)0.f; n2[j] = (v4f)0.f; }

    {
        const int s = s0 - 3;
        #pragma unroll
        for (int j = 0; j < 4; ++j)
            cur[j] = (s >= 0) ? *(const v4f*)(x + base + (size_t)s * C + j * 256) : (v4f)0.f;
        #pragma unroll
        for (int j = 0; j < 4; ++j)
            f1[j] = (s + 1 >= 0) ? *(const v4f*)(x + base + (size_t)(s + 1) * C + j * 256) : (v4f)0.f;
        #pragma unroll
        for (int j = 0; j < 4; ++j)
            f2[j] = (s + 2 >= 0) ? *(const v4f*)(x + base + (size_t)(s + 2) * C + j * 256) : (v4f)0.f;
    }

    for (int s = s0 - 3; s < send; ++s) {
        // Issue the deepest prefetch first (row s+3; s+3 >= s0 >= 0 always).
        v4f f3[4];
        const int sn = s + 3;
        if (sn < send) {
            #pragma unroll
            for (int j = 0; j < 4; ++j)
                f3[j] = *(const v4f*)(x + base + (size_t)sn * C + j * 256);
        } else {
            #pragma unroll
            for (int j = 0; j < 4; ++j) f3[j] = (v4f)0.f;
        }

        // Wave-local sum of squares of row s (16/lane + 6-step butterfly).
        v4f a = cur[0] * cur[0];
        a += cur[1] * cur[1];
        a += cur[2] * cur[2];
        a += cur[3] * cur[3];
        float local = a.x + a.y + a.z + a.w;
        #pragma unroll
        for (int off = 32; off > 0; off >>= 1)
            local += __shfl_xor(local, off, 64);
        const float invr = rsqrtf(local * (1.0f / D) + EPS);

        v4f n3[4];
        #pragma unroll
        for (int j = 0; j < 4; ++j)
            n3[j] = cur[j] * invr;

        if (s >= s0) {
            #pragma unroll
            for (int j = 0; j < 4; ++j) {
                v4f y = wt0[j] * n0[j] + wt1[j] * n1[j]
                      + wt2[j] * n2[j] + wt3[j] * n3[j];
                y.x *= __builtin_amdgcn_rcpf(1.f + __expf(-y.x));
                y.y *= __builtin_amdgcn_rcpf(1.f + __expf(-y.y));
                y.z *= __builtin_amdgcn_rcpf(1.f + __expf(-y.z));
                y.w *= __builtin_amdgcn_rcpf(1.f + __expf(-y.w));
                __builtin_nontemporal_store(y, (v4f*)(out + base + (size_t)s * C + j * 256));
            }
        }

        // Rotate pipeline (register renames after unroll — no scratch).
        #pragma unroll
        for (int j = 0; j < 4; ++j) {
            n0[j] = n1[j];  n1[j] = n2[j];  n2[j] = n3[j];
            cur[j] = f1[j]; f1[j] = f2[j];  f2[j] = f3[j];
        }
    }
}

extern "C" void kernel_launch(void* const* d_in, const int* in_sizes, int n_in,
                              void* d_out, int out_size, void* d_ws, size_t ws_size,
                              hipStream_t stream) {
    const float* x     = (const float*)d_in[0];
    const float* scale = (const float*)d_in[1];
    const float* w     = (const float*)d_in[2];
    float* out         = (float*)d_out;

    const int total_waves = (S / STRIP) * B * G;   // 2048
    dim3 grid(total_waves / 4);                    // 512 blocks of 4 waves
    dim3 block(256);
    shortconv_wave_kernel<<<grid, block, 0, stream>>>(x, scale, w, out);
}